// Round 4
// baseline (276.551 us; speedup 1.0000x reference)
//
#include <hip/hip_runtime.h>
#include <hip/hip_bf16.h>

#define NB 256
#define DD 65536
#define NN 41
#define GG 2048
#define OO 256
#define NO 10496
#define EE 512
#define NEG_SLOPE 0.2f

typedef __attribute__((ext_vector_type(8))) short bf16x8;
typedef __attribute__((ext_vector_type(4))) float f32x4;
typedef unsigned int u32;

// async global->LDS, 16B per lane. LDS dest must be wave-uniform base + lane*16.
__device__ __forceinline__ void gl_lds16(const __hip_bfloat16* gsrc, __hip_bfloat16* lds) {
    __builtin_amdgcn_global_load_lds((const __attribute__((address_space(1))) u32*)gsrc,
                                     (__attribute__((address_space(3))) u32*)lds, 16, 0, 0);
}

__device__ __forceinline__ u32 pack_bf2(float lo, float hi) {
    u32 a = (u32)__bfloat16_as_ushort(__float2bfloat16(lo));
    u32 b = (u32)__bfloat16_as_ushort(__float2bfloat16(hi));
    return a | (b << 16);
}

// ---- fused transpose + fp32->bf16 cast for BOTH W and W3 ----
// Chunk = [KC=256 k][64 o]. Transpose happens in registers at load time
// (thread owns input rows 2p,2p+1; packs k-pairs); LDS holds the final
// bf16 [64 o][256 k] tile; stores are 512B contiguous per output row,
// 1KB per wave store instruction (long DRAM write runs — the round-3
// short-chunk 4KB-pitch scatter is the suspected 2TB/s limiter).
// W: 41 slabs * (8 kc * 4 o) = 1312 blocks; W3: 41 kc * 8 o = 328 blocks.
__global__ __launch_bounds__(256) void transpose_both_k(const float* __restrict__ W,
                                                        const float* __restrict__ W3,
                                                        __hip_bfloat16* __restrict__ Wt,
                                                        __hip_bfloat16* __restrict__ W3t) {
    __shared__ u32 tb[64 * 128];  // [64 o][128 k-pair u32] = 32 KiB
    int bid = blockIdx.x;
    const float* src;
    __hip_bfloat16* dst;
    int K, Oc, kc0, o0;
    if (bid < NN * 32) {
        int z = bid >> 5;
        int rem = bid & 31;
        kc0 = (rem >> 2) * 256;
        o0 = (rem & 3) * 64;
        src = W + (size_t)z * GG * OO;
        dst = Wt + (size_t)z * GG * OO;
        K = GG; Oc = OO;
    } else {
        int rem = bid - NN * 32;
        kc0 = (rem >> 3) * 256;
        o0 = (rem & 7) * 64;
        src = W3; dst = W3t;
        K = NO; Oc = EE;
    }
    int t = threadIdx.x;
    int p = t & 127;            // k-pair index 0..127 (input rows 2p, 2p+1)
    int oh = (t >> 7) * 32;     // o-half base
    const float* r0 = src + (size_t)(kc0 + 2 * p) * Oc + o0 + oh;
    const float* r1 = r0 + Oc;
#pragma unroll
    for (int c = 0; c < 8; ++c) {
        float4 a = *(const float4*)&r0[c * 4];
        float4 b = *(const float4*)&r1[c * 4];
        // per-instr banks: unit%32 = p%32 -> 2 lanes/bank (free)
        tb[(oh + c * 4 + 0) * 128 + p] = pack_bf2(a.x, b.x);
        tb[(oh + c * 4 + 1) * 128 + p] = pack_bf2(a.y, b.y);
        tb[(oh + c * 4 + 2) * 128 + p] = pack_bf2(a.z, b.z);
        tb[(oh + c * 4 + 3) * 128 + p] = pack_bf2(a.w, b.w);
    }
    __syncthreads();
    // store: each wave instr covers 2 output rows x 512B = 1KB contiguous
    int w = t >> 6, l = t & 63;
    int lr = l >> 5;            // row within pair
    int ls = l & 31;            // 16B segment within 512B row
#pragma unroll
    for (int j = 0; j < 8; ++j) {
        int o = j * 8 + w * 2 + lr;
        uint4 v = *(const uint4*)&tb[o * 128 + ls * 4];
        *(uint4*)&dst[(size_t)(o0 + o) * K + kc0 + ls * 8] = v;
    }
}

// ---- gather, full row in 128 KiB dynamic LDS: one block per row b, 1024 thr (16 waves) ----
__global__ __launch_bounds__(1024) void gather_full_k(const float* __restrict__ x,
                                                      const int* __restrict__ idx,
                                                      __hip_bfloat16* __restrict__ g) {
    extern __shared__ __hip_bfloat16 xr[];  // 131072 bytes
    int b = blockIdx.x;
    int t = threadIdx.x;
    const float4* xv = (const float4*)(x + (size_t)b * DD);
#pragma unroll
    for (int i = 0; i < 16; ++i) {
        float4 v = xv[t + 1024 * i];
        short4 p;
        p.x = (short)__bfloat16_as_ushort(__float2bfloat16(v.x));
        p.y = (short)__bfloat16_as_ushort(__float2bfloat16(v.y));
        p.z = (short)__bfloat16_as_ushort(__float2bfloat16(v.z));
        p.w = (short)__bfloat16_as_ushort(__float2bfloat16(v.w));
        *(short4*)&xr[(t + 1024 * i) * 4] = p;
    }
    __syncthreads();
    const int4* idx4 = (const int4*)idx;
    for (int u = t; u < NN * GG / 4; u += 1024) {
        int4 ii = idx4[u];
        int n = u >> 9;
        int k = (u & 511) * 4;
        ushort4 o;
        o.x = __bfloat16_as_ushort(xr[ii.x]);
        o.y = __bfloat16_as_ushort(xr[ii.y]);
        o.z = __bfloat16_as_ushort(xr[ii.z]);
        o.w = __bfloat16_as_ushort(xr[ii.w]);
        *(ushort4*)&g[((size_t)n * NB + b) * GG + k] = o;
    }
}

// ---- fallback gather (half row in 64 KiB static LDS) ----
__global__ __launch_bounds__(512) void gather_half_k(const float* __restrict__ x,
                                                     const int* __restrict__ idx,
                                                     __hip_bfloat16* __restrict__ g) {
    __shared__ __align__(16) __hip_bfloat16 xr[32768];
    int b = blockIdx.x >> 1;
    int h = blockIdx.x & 1;
    int t = threadIdx.x;
    const float4* xv = (const float4*)(x + (size_t)b * DD + h * 32768);
#pragma unroll
    for (int i = 0; i < 16; ++i) {
        float4 v = xv[t + 512 * i];
        short4 p;
        p.x = (short)__bfloat16_as_ushort(__float2bfloat16(v.x));
        p.y = (short)__bfloat16_as_ushort(__float2bfloat16(v.y));
        p.z = (short)__bfloat16_as_ushort(__float2bfloat16(v.z));
        p.w = (short)__bfloat16_as_ushort(__float2bfloat16(v.w));
        *(short4*)&xr[(t + 512 * i) * 4] = p;
    }
    __syncthreads();
    const int4* idx4 = (const int4*)idx;
    for (int u = t; u < NN * GG / 4; u += 512) {
        int4 ii = idx4[u];
        int n = u >> 9;
        int k = (u & 511) * 4;
        __hip_bfloat16* dst = &g[((size_t)n * NB + b) * GG + k];
        if ((ii.x >> 15) == h) dst[0] = xr[ii.x & 32767];
        if ((ii.y >> 15) == h) dst[1] = xr[ii.y & 32767];
        if ((ii.z >> 15) == h) dst[2] = xr[ii.z & 32767];
        if ((ii.w >> 15) == h) dst[3] = xr[ii.w & 32767];
    }
}

// ---- GEMM1 split-K=4, double-buffered. grid 656 = 41n*2m*2o*4s;
// 256 thr = 4 waves, wave tile 64x64 (16 MFMA : 8 ds_read_b128);
// block tile 128x128, Kchunk 512, BK=32, 16 iters. bf16 partials.
// XCD-aware bijective swizzle: 656 = 8*82.
__global__ __launch_bounds__(256) void gemm1_k(const __hip_bfloat16* __restrict__ g,
                                               const __hip_bfloat16* __restrict__ Wt,
                                               __hip_bfloat16* __restrict__ part1) {
    int bid0 = blockIdx.x;
    int bid = (bid0 & 7) * 82 + (bid0 >> 3);
    int s = bid & 3;
    int o0 = ((bid >> 2) & 1) * 128;
    int m0 = ((bid >> 3) & 1) * 128;
    int n = bid >> 4;
    const __hip_bfloat16* srcA = g + ((size_t)n * NB + m0) * GG + s * 512;
    const __hip_bfloat16* srcB = Wt + ((size_t)n * OO + o0) * GG + s * 512;
    __shared__ __align__(16) __hip_bfloat16 lA[2][128 * 32];
    __shared__ __align__(16) __hip_bfloat16 lB[2][128 * 32];
    int t = threadIdx.x;
    int lane = t & 63, w = t >> 6;
    int mw = (w >> 1) * 64, ow = (w & 1) * 64;
    int lrow = lane & 15, quad = lane >> 4;
    int r0 = t >> 2, q0 = (t & 3) * 8;  // staging: 2 chunks/thread/operand
    f32x4 acc[4][4] = {};

    gl_lds16(srcA + (size_t)r0 * GG + q0, &lA[0][t * 8]);
    gl_lds16(srcA + (size_t)(r0 + 64) * GG + q0, &lA[0][(t + 256) * 8]);
    gl_lds16(srcB + (size_t)r0 * GG + q0, &lB[0][t * 8]);
    gl_lds16(srcB + (size_t)(r0 + 64) * GG + q0, &lB[0][(t + 256) * 8]);
    __syncthreads();
#pragma unroll 1
    for (int it = 0; it < 16; ++it) {
        int cur = it & 1;
        if (it + 1 < 16) {
            int k1 = (it + 1) * 32;
            gl_lds16(srcA + (size_t)r0 * GG + k1 + q0, &lA[1 - cur][t * 8]);
            gl_lds16(srcA + (size_t)(r0 + 64) * GG + k1 + q0, &lA[1 - cur][(t + 256) * 8]);
            gl_lds16(srcB + (size_t)r0 * GG + k1 + q0, &lB[1 - cur][t * 8]);
            gl_lds16(srcB + (size_t)(r0 + 64) * GG + k1 + q0, &lB[1 - cur][(t + 256) * 8]);
        }
        bf16x8 af[4];
#pragma unroll
        for (int fm = 0; fm < 4; ++fm)
            af[fm] = *(const bf16x8*)&lA[cur][(mw + fm * 16 + lrow) * 32 + quad * 8];
#pragma unroll
        for (int fn = 0; fn < 4; ++fn) {
            bf16x8 bfr = *(const bf16x8*)&lB[cur][(ow + fn * 16 + lrow) * 32 + quad * 8];
#pragma unroll
            for (int fm = 0; fm < 4; ++fm)
                acc[fm][fn] = __builtin_amdgcn_mfma_f32_16x16x32_bf16(af[fm], bfr, acc[fm][fn], 0, 0, 0);
        }
        __syncthreads();  // safe to overwrite buf[cur] next iter; prefetch drained
    }
    // C/D layout: col=lane&15, row=quad*4+reg
#pragma unroll
    for (int fm = 0; fm < 4; ++fm) {
#pragma unroll
        for (int fn = 0; fn < 4; ++fn) {
            int col = o0 + ow + fn * 16 + lrow;
#pragma unroll
            for (int r = 0; r < 4; ++r) {
                int row = m0 + mw + fm * 16 + quad * 4 + r;
                part1[((size_t)s * NB + row) * NO + n * OO + col] = __float2bfloat16(acc[fm][fn][r]);
            }
        }
    }
}

// ---- combine 4 bf16 GEMM1 partials + bias -> h bf16 ----
__global__ __launch_bounds__(256) void combine1_k(const __hip_bfloat16* __restrict__ part1,
                                                  const float* __restrict__ bias,
                                                  __hip_bfloat16* __restrict__ h) {
    int j4 = blockIdx.x * 256 + threadIdx.x;  // 4-elem group over NB*NO/4
    int jj = j4 % (NO / 4);
    float4 a = ((const float4*)bias)[jj];
#pragma unroll
    for (int s = 0; s < 4; ++s) {
        ushort4 p = *(const ushort4*)&part1[(size_t)s * NB * NO + (size_t)j4 * 4];
        a.x += __bfloat162float(__ushort_as_bfloat16(p.x));
        a.y += __bfloat162float(__ushort_as_bfloat16(p.y));
        a.z += __bfloat162float(__ushort_as_bfloat16(p.z));
        a.w += __bfloat162float(__ushort_as_bfloat16(p.w));
    }
    ushort4 o;
    o.x = __bfloat16_as_ushort(__float2bfloat16(a.x));
    o.y = __bfloat16_as_ushort(__float2bfloat16(a.y));
    o.z = __bfloat16_as_ushort(__float2bfloat16(a.z));
    o.w = __bfloat16_as_ushort(__float2bfloat16(a.w));
    *(ushort4*)&h[(size_t)j4 * 4] = o;
}

// ---- GEMM2 split-K=41, double-buffered. grid 656 = 41s*2m*8e;
// 256 thr = 4 waves, wave tile 64x32; block 128x64, Kchunk 256, 8 iters.
// XCD-aware bijective swizzle: 656 = 8*82.
__global__ __launch_bounds__(256) void gemm2_k(const __hip_bfloat16* __restrict__ h,
                                               const __hip_bfloat16* __restrict__ W3t,
                                               float* __restrict__ part) {
    int bid0 = blockIdx.x;
    int bid = (bid0 & 7) * 82 + (bid0 >> 3);
    int e0 = (bid & 7) * 64;
    int m0 = ((bid >> 3) & 1) * 128;
    int s = bid >> 4;  // 0..40
    const __hip_bfloat16* srcA = h + (size_t)m0 * NO + s * 256;
    const __hip_bfloat16* srcB = W3t + (size_t)e0 * NO + s * 256;
    __shared__ __align__(16) __hip_bfloat16 lA[2][128 * 32];
    __shared__ __align__(16) __hip_bfloat16 lB[2][64 * 32];
    int t = threadIdx.x;
    int lane = t & 63, w = t >> 6;
    int mw = (w >> 1) * 64, ew = (w & 1) * 32;
    int lrow = lane & 15, quad = lane >> 4;
    int rA = t >> 2, qA = (t & 3) * 8;   // A: 2 chunks/thread
    int rB = t >> 2, qB = (t & 3) * 8;   // B: 64 rows -> 1 chunk/thread
    f32x4 acc[4][2] = {};

    gl_lds16(srcA + (size_t)rA * NO + qA, &lA[0][t * 8]);
    gl_lds16(srcA + (size_t)(rA + 64) * NO + qA, &lA[0][(t + 256) * 8]);
    gl_lds16(srcB + (size_t)(rB & 63) * NO + qB, &lB[0][t * 8]);
    __syncthreads();
#pragma unroll 1
    for (int it = 0; it < 8; ++it) {
        int cur = it & 1;
        if (it + 1 < 8) {
            int k1 = (it + 1) * 32;
            gl_lds16(srcA + (size_t)rA * NO + k1 + qA, &lA[1 - cur][t * 8]);
            gl_lds16(srcA + (size_t)(rA + 64) * NO + k1 + qA, &lA[1 - cur][(t + 256) * 8]);
            gl_lds16(srcB + (size_t)(rB & 63) * NO + k1 + qB, &lB[1 - cur][t * 8]);
        }
        bf16x8 af[4];
#pragma unroll
        for (int fm = 0; fm < 4; ++fm)
            af[fm] = *(const bf16x8*)&lA[cur][(mw + fm * 16 + lrow) * 32 + quad * 8];
#pragma unroll
        for (int fn = 0; fn < 2; ++fn) {
            bf16x8 bfr = *(const bf16x8*)&lB[cur][(ew + fn * 16 + lrow) * 32 + quad * 8];
#pragma unroll
            for (int fm = 0; fm < 4; ++fm)
                acc[fm][fn] = __builtin_amdgcn_mfma_f32_16x16x32_bf16(af[fm], bfr, acc[fm][fn], 0, 0, 0);
        }
        __syncthreads();
    }
#pragma unroll
    for (int fm = 0; fm < 4; ++fm) {
#pragma unroll
        for (int fn = 0; fn < 2; ++fn) {
            int e = e0 + ew + fn * 16 + lrow;
#pragma unroll
            for (int r = 0; r < 4; ++r) {
                int row = m0 + mw + fm * 16 + quad * 4 + r;
                part[((size_t)s * NB + row) * EE + e] = acc[fm][fn][r];
            }
        }
    }
}

// ---- reduce partials + bias + leaky relu; 256 blocks x 128 thr = full CU coverage ----
__global__ __launch_bounds__(128) void reduce_k(const float* __restrict__ part,
                                                const float* __restrict__ b3,
                                                float* __restrict__ out) {
    int j = blockIdx.x * 128 + threadIdx.x;  // float4 index over 256*512/4 = 32768
    float4 a = make_float4(0.f, 0.f, 0.f, 0.f);
    for (int s = 0; s < NN; ++s) {
        float4 v = ((const float4*)part)[(size_t)s * (NB * EE / 4) + j];
        a.x += v.x; a.y += v.y; a.z += v.z; a.w += v.w;
    }
    float4 bv = ((const float4*)b3)[j & 127];
    a.x += bv.x; a.y += bv.y; a.z += bv.z; a.w += bv.w;
    a.x = a.x >= 0.f ? a.x : NEG_SLOPE * a.x;
    a.y = a.y >= 0.f ? a.y : NEG_SLOPE * a.y;
    a.z = a.z >= 0.f ? a.z : NEG_SLOPE * a.z;
    a.w = a.w >= 0.f ? a.w : NEG_SLOPE * a.w;
    ((float4*)out)[j] = a;
}

extern "C" void kernel_launch(void* const* d_in, const int* in_sizes, int n_in,
                              void* d_out, int out_size, void* d_ws, size_t ws_size,
                              hipStream_t stream) {
    const float* x = (const float*)d_in[0];
    const int* idx = (const int*)d_in[1];
    const float* W = (const float*)d_in[2];
    const float* bias = (const float*)d_in[3];
    const float* W3 = (const float*)d_in[4];
    const float* b3 = (const float*)d_in[5];
    float* out = (float*)d_out;

    char* ws = (char*)d_ws;
    const size_t g_off = 0;
    const size_t g_sz = (size_t)NN * NB * GG * 2;
    const size_t wt_off = g_off + g_sz;
    const size_t wt_sz = (size_t)NN * GG * OO * 2;
    const size_t w3t_off = wt_off + wt_sz;
    const size_t w3t_sz = (size_t)NO * EE * 2;
    const size_t h_off = w3t_off + w3t_sz;
    const size_t h_sz = (size_t)NB * NO * 2;
    const size_t p_off = h_off + h_sz;
    // part1 (4 bf16 planes = 21.5 MB) aliases part (41*NB*EE*4 = 21.5 MB):
    // part1 dead after combine1_k, before gemm2_k writes part.

    __hip_bfloat16* g = (__hip_bfloat16*)(ws + g_off);
    __hip_bfloat16* Wt = (__hip_bfloat16*)(ws + wt_off);
    __hip_bfloat16* W3t = (__hip_bfloat16*)(ws + w3t_off);
    __hip_bfloat16* h = (__hip_bfloat16*)(ws + h_off);
    __hip_bfloat16* part1 = (__hip_bfloat16*)(ws + p_off);
    float* part = (float*)(ws + p_off);

    // W (41,2048,256) -> Wt (41,256,2048) bf16  AND  W3 (10496,512) -> W3t (512,10496) bf16
    // grid: 41*32 W-chunks + 41*8 W3-chunks = 1640, each [256k][64o]
    transpose_both_k<<<dim3(NN * 32 + NN * 8), 256, 0, stream>>>(W, W3, Wt, W3t);
    // gather: full 128 KiB row in dynamic LDS if allowed (1024 thr = 16 waves/CU), else fallback
    hipError_t aerr = hipFuncSetAttribute(reinterpret_cast<const void*>(gather_full_k),
                                          hipFuncAttributeMaxDynamicSharedMemorySize, 131072);
    if (aerr == hipSuccess) {
        gather_full_k<<<dim3(NB), 1024, 131072, stream>>>(x, idx, g);
    } else {
        gather_half_k<<<dim3(512), 512, 0, stream>>>(x, idx, g);
    }
    // GEMM1 split-K=4, double-buffered, bf16 partials
    gemm1_k<<<dim3(656), 256, 0, stream>>>(g, Wt, part1);
    // combine 4 partials + bias -> h bf16
    combine1_k<<<dim3(NB * NO / 4 / 256), 256, 0, stream>>>(part1, bias, h);
    // GEMM2 split-K, double-buffered
    gemm2_k<<<dim3(656), 256, 0, stream>>>(h, W3t, part);
    // reduce + bias + leaky relu
    reduce_k<<<dim3(256), 128, 0, stream>>>(part, b3, out);
}

// Round 5
// 266.178 us; speedup vs baseline: 1.0390x; 1.0390x over previous
//
#include <hip/hip_runtime.h>
#include <hip/hip_bf16.h>

#define NB 256
#define DD 65536
#define NN 41
#define GG 2048
#define OO 256
#define NO 10496
#define EE 512
#define NEG_SLOPE 0.2f

typedef __attribute__((ext_vector_type(8))) short bf16x8;
typedef __attribute__((ext_vector_type(4))) float f32x4;
typedef unsigned int u32;

// async global->LDS, 16B per lane. LDS dest must be wave-uniform base + lane*16.
__device__ __forceinline__ void gl_lds16(const __hip_bfloat16* gsrc, __hip_bfloat16* lds) {
    __builtin_amdgcn_global_load_lds((const __attribute__((address_space(1))) u32*)gsrc,
                                     (__attribute__((address_space(3))) u32*)lds, 16, 0, 0);
}

__device__ __forceinline__ u32 pack_bf2(float lo, float hi) {
    u32 a = (u32)__bfloat16_as_ushort(__float2bfloat16(lo));
    u32 b = (u32)__bfloat16_as_ushort(__float2bfloat16(hi));
    return a | (b << 16);
}

// ---- transpose + cast for W3 ONLY (W-transpose is fused into gemm1 now) ----
// W3 (10496,512) -> W3t (512,10496): 41 kc * 8 o = 328 blocks of [256 k][64 o].
__global__ __launch_bounds__(256) void transpose_w3_k(const float* __restrict__ W3,
                                                      __hip_bfloat16* __restrict__ W3t) {
    __shared__ u32 tb[64 * 128];  // [64 o][128 k-pair u32] = 32 KiB
    int rem = blockIdx.x;
    int kc0 = (rem >> 3) * 256;
    int o0 = (rem & 7) * 64;
    const int K = NO, Oc = EE;
    int t = threadIdx.x;
    int p = t & 127;            // k-pair index (input rows 2p, 2p+1)
    int oh = (t >> 7) * 32;     // o-half base
    const float* r0 = W3 + (size_t)(kc0 + 2 * p) * Oc + o0 + oh;
    const float* r1 = r0 + Oc;
#pragma unroll
    for (int c = 0; c < 8; ++c) {
        float4 a = *(const float4*)&r0[c * 4];
        float4 b = *(const float4*)&r1[c * 4];
        tb[(oh + c * 4 + 0) * 128 + p] = pack_bf2(a.x, b.x);
        tb[(oh + c * 4 + 1) * 128 + p] = pack_bf2(a.y, b.y);
        tb[(oh + c * 4 + 2) * 128 + p] = pack_bf2(a.z, b.z);
        tb[(oh + c * 4 + 3) * 128 + p] = pack_bf2(a.w, b.w);
    }
    __syncthreads();
    int w = t >> 6, l = t & 63;
    int lr = l >> 5;
    int ls = l & 31;
#pragma unroll
    for (int j = 0; j < 8; ++j) {
        int o = j * 8 + w * 2 + lr;
        uint4 v = *(const uint4*)&tb[o * 128 + ls * 4];
        *(uint4*)&W3t[(size_t)(o0 + o) * K + kc0 + ls * 8] = v;
    }
}

// ---- gather, full row in 128 KiB dynamic LDS: one block per row b, 1024 thr (16 waves) ----
__global__ __launch_bounds__(1024) void gather_full_k(const float* __restrict__ x,
                                                      const int* __restrict__ idx,
                                                      __hip_bfloat16* __restrict__ g) {
    extern __shared__ __hip_bfloat16 xr[];  // 131072 bytes
    int b = blockIdx.x;
    int t = threadIdx.x;
    const float4* xv = (const float4*)(x + (size_t)b * DD);
#pragma unroll
    for (int i = 0; i < 16; ++i) {
        float4 v = xv[t + 1024 * i];
        short4 p;
        p.x = (short)__bfloat16_as_ushort(__float2bfloat16(v.x));
        p.y = (short)__bfloat16_as_ushort(__float2bfloat16(v.y));
        p.z = (short)__bfloat16_as_ushort(__float2bfloat16(v.z));
        p.w = (short)__bfloat16_as_ushort(__float2bfloat16(v.w));
        *(short4*)&xr[(t + 1024 * i) * 4] = p;
    }
    __syncthreads();
    const int4* idx4 = (const int4*)idx;
    for (int u = t; u < NN * GG / 4; u += 1024) {
        int4 ii = idx4[u];
        int n = u >> 9;
        int k = (u & 511) * 4;
        ushort4 o;
        o.x = __bfloat16_as_ushort(xr[ii.x]);
        o.y = __bfloat16_as_ushort(xr[ii.y]);
        o.z = __bfloat16_as_ushort(xr[ii.z]);
        o.w = __bfloat16_as_ushort(xr[ii.w]);
        *(ushort4*)&g[((size_t)n * NB + b) * GG + k] = o;
    }
}

// ---- fallback gather (half row in 64 KiB static LDS) ----
__global__ __launch_bounds__(512) void gather_half_k(const float* __restrict__ x,
                                                     const int* __restrict__ idx,
                                                     __hip_bfloat16* __restrict__ g) {
    __shared__ __align__(16) __hip_bfloat16 xr[32768];
    int b = blockIdx.x >> 1;
    int h = blockIdx.x & 1;
    int t = threadIdx.x;
    const float4* xv = (const float4*)(x + (size_t)b * DD + h * 32768);
#pragma unroll
    for (int i = 0; i < 16; ++i) {
        float4 v = xv[t + 512 * i];
        short4 p;
        p.x = (short)__bfloat16_as_ushort(__float2bfloat16(v.x));
        p.y = (short)__bfloat16_as_ushort(__float2bfloat16(v.y));
        p.z = (short)__bfloat16_as_ushort(__float2bfloat16(v.z));
        p.w = (short)__bfloat16_as_ushort(__float2bfloat16(v.w));
        *(short4*)&xr[(t + 512 * i) * 4] = p;
    }
    __syncthreads();
    const int4* idx4 = (const int4*)idx;
    for (int u = t; u < NN * GG / 4; u += 512) {
        int4 ii = idx4[u];
        int n = u >> 9;
        int k = (u & 511) * 4;
        __hip_bfloat16* dst = &g[((size_t)n * NB + b) * GG + k];
        if ((ii.x >> 15) == h) dst[0] = xr[ii.x & 32767];
        if ((ii.y >> 15) == h) dst[1] = xr[ii.y & 32767];
        if ((ii.z >> 15) == h) dst[2] = xr[ii.z & 32767];
        if ((ii.w >> 15) == h) dst[3] = xr[ii.w & 32767];
    }
}

// ---- GEMM1 split-K=4, fused W cast+transpose in B-staging. grid 656 = 41n*2m*2o*4s.
// A: g bf16 via gl_lds16 (unchanged). B: W fp32 rows loaded o-contiguous,
// k-pairs packed to bf16x2 in registers, ds_write_b32 into [128 o][16 kpair]
// with 2-bit XOR swizzle (4-way write conflict). Frag reads apply same XOR.
// Eliminates Wt entirely (the standalone W transpose was pinned at 2 TB/s).
__global__ __launch_bounds__(256) void gemm1_k(const __hip_bfloat16* __restrict__ g,
                                               const float* __restrict__ W,
                                               __hip_bfloat16* __restrict__ part1) {
    int bid0 = blockIdx.x;
    int bid = (bid0 & 7) * 82 + (bid0 >> 3);
    int s = bid & 3;
    int o0 = ((bid >> 2) & 1) * 128;
    int m0 = ((bid >> 3) & 1) * 128;
    int n = bid >> 4;
    const __hip_bfloat16* srcA = g + ((size_t)n * NB + m0) * GG + s * 512;
    const float* srcB = W + ((size_t)n * GG + s * 512) * OO + o0;  // [k][o0..o0+128)
    __shared__ __align__(16) __hip_bfloat16 lA[2][128 * 32];
    __shared__ __align__(16) __hip_bfloat16 lB[2][128 * 32];
    int t = threadIdx.x;
    int lane = t & 63, w = t >> 6;
    int mw = (w >> 1) * 64, ow = (w & 1) * 64;
    int lrow = lane & 15, quad = lane >> 4;
    int r0 = t >> 2, q0 = (t & 3) * 8;  // A staging
    // B staging: thread owns k-pair bp (rows 2bp,2bp+1), col octet boq
    int bp = t >> 4;            // 0..15
    int boq = t & 15;           // cols boq*8..boq*8+7
    int bswz = (boq & 3) << 2;  // XOR on kpair index, multiples of 4
    const float* wb0 = srcB + (size_t)(2 * bp) * OO + boq * 8;
    f32x4 acc[4][4] = {};

    // prologue: stage B tile 0 + A tile 0
    {
        float4 a0 = *(const float4*)&wb0[0];
        float4 a1 = *(const float4*)&wb0[4];
        float4 b0 = *(const float4*)&wb0[OO];
        float4 b1 = *(const float4*)&wb0[OO + 4];
        u32* d = (u32*)&lB[0][0];
        int ob = boq * 8;
        int pw = bp ^ bswz;
        d[(ob + 0) * 16 + pw] = pack_bf2(a0.x, b0.x);
        d[(ob + 1) * 16 + pw] = pack_bf2(a0.y, b0.y);
        d[(ob + 2) * 16 + pw] = pack_bf2(a0.z, b0.z);
        d[(ob + 3) * 16 + pw] = pack_bf2(a0.w, b0.w);
        d[(ob + 4) * 16 + pw] = pack_bf2(a1.x, b1.x);
        d[(ob + 5) * 16 + pw] = pack_bf2(a1.y, b1.y);
        d[(ob + 6) * 16 + pw] = pack_bf2(a1.z, b1.z);
        d[(ob + 7) * 16 + pw] = pack_bf2(a1.w, b1.w);
    }
    gl_lds16(srcA + (size_t)r0 * GG + q0, &lA[0][t * 8]);
    gl_lds16(srcA + (size_t)(r0 + 64) * GG + q0, &lA[0][(t + 256) * 8]);
    __syncthreads();
#pragma unroll 1
    for (int it = 0; it < 16; ++it) {
        int cur = it & 1;
        float4 a0, a1, b0, b1;
        bool pf = (it + 1 < 16);
        if (pf) {
            int k1 = (it + 1) * 32;
            const float* wn = wb0 + (size_t)k1 * OO;
            a0 = *(const float4*)&wn[0];        // issue early (T14): consumed after MFMAs
            a1 = *(const float4*)&wn[4];
            b0 = *(const float4*)&wn[OO];
            b1 = *(const float4*)&wn[OO + 4];
            gl_lds16(srcA + (size_t)r0 * GG + k1 + q0, &lA[1 - cur][t * 8]);
            gl_lds16(srcA + (size_t)(r0 + 64) * GG + k1 + q0, &lA[1 - cur][(t + 256) * 8]);
        }
        bf16x8 af[4];
#pragma unroll
        for (int fm = 0; fm < 4; ++fm)
            af[fm] = *(const bf16x8*)&lA[cur][(mw + fm * 16 + lrow) * 32 + quad * 8];
        const u32* lbu = (const u32*)&lB[cur][0];
#pragma unroll
        for (int fn = 0; fn < 4; ++fn) {
            int orow = ow + fn * 16 + lrow;
            int fsw = ((orow >> 3) & 3) << 2;
            bf16x8 bfr = *(const bf16x8*)&lbu[orow * 16 + (quad * 4 ^ fsw)];
#pragma unroll
            for (int fm = 0; fm < 4; ++fm)
                acc[fm][fn] = __builtin_amdgcn_mfma_f32_16x16x32_bf16(af[fm], bfr, acc[fm][fn], 0, 0, 0);
        }
        if (pf) {
            u32* d = (u32*)&lB[1 - cur][0];
            int ob = boq * 8;
            int pw = bp ^ bswz;
            d[(ob + 0) * 16 + pw] = pack_bf2(a0.x, b0.x);
            d[(ob + 1) * 16 + pw] = pack_bf2(a0.y, b0.y);
            d[(ob + 2) * 16 + pw] = pack_bf2(a0.z, b0.z);
            d[(ob + 3) * 16 + pw] = pack_bf2(a0.w, b0.w);
            d[(ob + 4) * 16 + pw] = pack_bf2(a1.x, b1.x);
            d[(ob + 5) * 16 + pw] = pack_bf2(a1.y, b1.y);
            d[(ob + 6) * 16 + pw] = pack_bf2(a1.z, b1.z);
            d[(ob + 7) * 16 + pw] = pack_bf2(a1.w, b1.w);
        }
        __syncthreads();
    }
    // C/D layout: col=lane&15, row=quad*4+reg
#pragma unroll
    for (int fm = 0; fm < 4; ++fm) {
#pragma unroll
        for (int fn = 0; fn < 4; ++fn) {
            int col = o0 + ow + fn * 16 + lrow;
#pragma unroll
            for (int r = 0; r < 4; ++r) {
                int row = m0 + mw + fm * 16 + quad * 4 + r;
                part1[((size_t)s * NB + row) * NO + n * OO + col] = __float2bfloat16(acc[fm][fn][r]);
            }
        }
    }
}

// ---- combine 4 bf16 GEMM1 partials + bias -> h bf16 ----
__global__ __launch_bounds__(256) void combine1_k(const __hip_bfloat16* __restrict__ part1,
                                                  const float* __restrict__ bias,
                                                  __hip_bfloat16* __restrict__ h) {
    int j4 = blockIdx.x * 256 + threadIdx.x;  // 4-elem group over NB*NO/4
    int jj = j4 % (NO / 4);
    float4 a = ((const float4*)bias)[jj];
#pragma unroll
    for (int s = 0; s < 4; ++s) {
        ushort4 p = *(const ushort4*)&part1[(size_t)s * NB * NO + (size_t)j4 * 4];
        a.x += __bfloat162float(__ushort_as_bfloat16(p.x));
        a.y += __bfloat162float(__ushort_as_bfloat16(p.y));
        a.z += __bfloat162float(__ushort_as_bfloat16(p.z));
        a.w += __bfloat162float(__ushort_as_bfloat16(p.w));
    }
    ushort4 o;
    o.x = __bfloat16_as_ushort(__float2bfloat16(a.x));
    o.y = __bfloat16_as_ushort(__float2bfloat16(a.y));
    o.z = __bfloat16_as_ushort(__float2bfloat16(a.z));
    o.w = __bfloat16_as_ushort(__float2bfloat16(a.w));
    *(ushort4*)&h[(size_t)j4 * 4] = o;
}

// ---- GEMM2 split-K=41, double-buffered. grid 656 = 41s*2m*8e;
// 256 thr = 4 waves, wave tile 64x32; block 128x64, Kchunk 256, 8 iters.
// XCD-aware bijective swizzle: 656 = 8*82.
__global__ __launch_bounds__(256) void gemm2_k(const __hip_bfloat16* __restrict__ h,
                                               const __hip_bfloat16* __restrict__ W3t,
                                               float* __restrict__ part) {
    int bid0 = blockIdx.x;
    int bid = (bid0 & 7) * 82 + (bid0 >> 3);
    int e0 = (bid & 7) * 64;
    int m0 = ((bid >> 3) & 1) * 128;
    int s = bid >> 4;  // 0..40
    const __hip_bfloat16* srcA = h + (size_t)m0 * NO + s * 256;
    const __hip_bfloat16* srcB = W3t + (size_t)e0 * NO + s * 256;
    __shared__ __align__(16) __hip_bfloat16 lA[2][128 * 32];
    __shared__ __align__(16) __hip_bfloat16 lB[2][64 * 32];
    int t = threadIdx.x;
    int lane = t & 63, w = t >> 6;
    int mw = (w >> 1) * 64, ew = (w & 1) * 32;
    int lrow = lane & 15, quad = lane >> 4;
    int rA = t >> 2, qA = (t & 3) * 8;
    int rB = t >> 2, qB = (t & 3) * 8;
    f32x4 acc[4][2] = {};

    gl_lds16(srcA + (size_t)rA * NO + qA, &lA[0][t * 8]);
    gl_lds16(srcA + (size_t)(rA + 64) * NO + qA, &lA[0][(t + 256) * 8]);
    gl_lds16(srcB + (size_t)(rB & 63) * NO + qB, &lB[0][t * 8]);
    __syncthreads();
#pragma unroll 1
    for (int it = 0; it < 8; ++it) {
        int cur = it & 1;
        if (it + 1 < 8) {
            int k1 = (it + 1) * 32;
            gl_lds16(srcA + (size_t)rA * NO + k1 + qA, &lA[1 - cur][t * 8]);
            gl_lds16(srcA + (size_t)(rA + 64) * NO + k1 + qA, &lA[1 - cur][(t + 256) * 8]);
            gl_lds16(srcB + (size_t)(rB & 63) * NO + k1 + qB, &lB[1 - cur][t * 8]);
        }
        bf16x8 af[4];
#pragma unroll
        for (int fm = 0; fm < 4; ++fm)
            af[fm] = *(const bf16x8*)&lA[cur][(mw + fm * 16 + lrow) * 32 + quad * 8];
#pragma unroll
        for (int fn = 0; fn < 2; ++fn) {
            bf16x8 bfr = *(const bf16x8*)&lB[cur][(ew + fn * 16 + lrow) * 32 + quad * 8];
#pragma unroll
            for (int fm = 0; fm < 4; ++fm)
                acc[fm][fn] = __builtin_amdgcn_mfma_f32_16x16x32_bf16(af[fm], bfr, acc[fm][fn], 0, 0, 0);
        }
        __syncthreads();
    }
#pragma unroll
    for (int fm = 0; fm < 4; ++fm) {
#pragma unroll
        for (int fn = 0; fn < 2; ++fn) {
            int e = e0 + ew + fn * 16 + lrow;
#pragma unroll
            for (int r = 0; r < 4; ++r) {
                int row = m0 + mw + fm * 16 + quad * 4 + r;
                part[((size_t)s * NB + row) * EE + e] = acc[fm][fn][r];
            }
        }
    }
}

// ---- reduce partials + bias + leaky relu; 256 blocks x 128 thr ----
__global__ __launch_bounds__(128) void reduce_k(const float* __restrict__ part,
                                                const float* __restrict__ b3,
                                                float* __restrict__ out) {
    int j = blockIdx.x * 128 + threadIdx.x;
    float4 a = make_float4(0.f, 0.f, 0.f, 0.f);
    for (int s = 0; s < NN; ++s) {
        float4 v = ((const float4*)part)[(size_t)s * (NB * EE / 4) + j];
        a.x += v.x; a.y += v.y; a.z += v.z; a.w += v.w;
    }
    float4 bv = ((const float4*)b3)[j & 127];
    a.x += bv.x; a.y += bv.y; a.z += bv.z; a.w += bv.w;
    a.x = a.x >= 0.f ? a.x : NEG_SLOPE * a.x;
    a.y = a.y >= 0.f ? a.y : NEG_SLOPE * a.y;
    a.z = a.z >= 0.f ? a.z : NEG_SLOPE * a.z;
    a.w = a.w >= 0.f ? a.w : NEG_SLOPE * a.w;
    ((float4*)out)[j] = a;
}

extern "C" void kernel_launch(void* const* d_in, const int* in_sizes, int n_in,
                              void* d_out, int out_size, void* d_ws, size_t ws_size,
                              hipStream_t stream) {
    const float* x = (const float*)d_in[0];
    const int* idx = (const int*)d_in[1];
    const float* W = (const float*)d_in[2];
    const float* bias = (const float*)d_in[3];
    const float* W3 = (const float*)d_in[4];
    const float* b3 = (const float*)d_in[5];
    float* out = (float*)d_out;

    char* ws = (char*)d_ws;
    const size_t g_off = 0;
    const size_t g_sz = (size_t)NN * NB * GG * 2;
    const size_t wt_off = g_off + g_sz;           // (unused slot kept for layout stability)
    const size_t wt_sz = (size_t)NN * GG * OO * 2;
    const size_t w3t_off = wt_off + wt_sz;
    const size_t w3t_sz = (size_t)NO * EE * 2;
    const size_t h_off = w3t_off + w3t_sz;
    const size_t h_sz = (size_t)NB * NO * 2;
    const size_t p_off = h_off + h_sz;
    // part1 (4 bf16 planes = 21.5 MB) aliases part (41*NB*EE*4 = 21.5 MB).

    __hip_bfloat16* g = (__hip_bfloat16*)(ws + g_off);
    __hip_bfloat16* W3t = (__hip_bfloat16*)(ws + w3t_off);
    __hip_bfloat16* h = (__hip_bfloat16*)(ws + h_off);
    __hip_bfloat16* part1 = (__hip_bfloat16*)(ws + p_off);
    float* part = (float*)(ws + p_off);

    // W3 (10496,512) -> W3t (512,10496) bf16 (W-transpose is gone — fused into gemm1)
    transpose_w3_k<<<dim3(NN * 8), 256, 0, stream>>>(W3, W3t);
    // gather: full 128 KiB row in dynamic LDS if allowed (1024 thr), else fallback
    hipError_t aerr = hipFuncSetAttribute(reinterpret_cast<const void*>(gather_full_k),
                                          hipFuncAttributeMaxDynamicSharedMemorySize, 131072);
    if (aerr == hipSuccess) {
        gather_full_k<<<dim3(NB), 1024, 131072, stream>>>(x, idx, g);
    } else {
        gather_half_k<<<dim3(512), 512, 0, stream>>>(x, idx, g);
    }
    // GEMM1 split-K=4, B staged directly from W fp32 (fused cast+transpose)
    gemm1_k<<<dim3(656), 256, 0, stream>>>(g, W, part1);
    // combine 4 partials + bias -> h bf16
    combine1_k<<<dim3(NB * NO / 4 / 256), 256, 0, stream>>>(part1, bias, h);
    // GEMM2 split-K, double-buffered
    gemm2_k<<<dim3(656), 256, 0, stream>>>(h, W3t, part);
    // reduce + bias + leaky relu
    reduce_k<<<dim3(256), 128, 0, stream>>>(part, b3, out);
}

// Round 6
// 265.261 us; speedup vs baseline: 1.0426x; 1.0035x over previous
//
#include <hip/hip_runtime.h>
#include <hip/hip_bf16.h>

#define NB 256
#define DD 65536
#define NN 41
#define GG 2048
#define OO 256
#define NO 10496
#define EE 512
#define NEG_SLOPE 0.2f

typedef __attribute__((ext_vector_type(8))) short bf16x8;
typedef __attribute__((ext_vector_type(4))) float f32x4;
typedef unsigned int u32;

// async global->LDS, 16B per lane. LDS dest must be wave-uniform base + lane*16.
__device__ __forceinline__ void gl_lds16(const __hip_bfloat16* gsrc, __hip_bfloat16* lds) {
    __builtin_amdgcn_global_load_lds((const __attribute__((address_space(1))) u32*)gsrc,
                                     (__attribute__((address_space(3))) u32*)lds, 16, 0, 0);
}

__device__ __forceinline__ u32 pack_bf2(float lo, float hi) {
    u32 a = (u32)__bfloat16_as_ushort(__float2bfloat16(lo));
    u32 b = (u32)__bfloat16_as_ushort(__float2bfloat16(hi));
    return a | (b << 16);
}

// ---- transpose + cast for W3 ONLY (W-transpose is fused into gemm1) ----
// W3 (10496,512) -> W3t (512,10496): 41 kc * 8 o = 328 blocks of [256 k][64 o].
__global__ __launch_bounds__(256) void transpose_w3_k(const float* __restrict__ W3,
                                                      __hip_bfloat16* __restrict__ W3t) {
    __shared__ u32 tb[64 * 128];  // [64 o][128 k-pair u32] = 32 KiB
    int rem = blockIdx.x;
    int kc0 = (rem >> 3) * 256;
    int o0 = (rem & 7) * 64;
    const int K = NO, Oc = EE;
    int t = threadIdx.x;
    int p = t & 127;            // k-pair index (input rows 2p, 2p+1)
    int oh = (t >> 7) * 32;     // o-half base
    const float* r0 = W3 + (size_t)(kc0 + 2 * p) * Oc + o0 + oh;
    const float* r1 = r0 + Oc;
#pragma unroll
    for (int c = 0; c < 8; ++c) {
        float4 a = *(const float4*)&r0[c * 4];
        float4 b = *(const float4*)&r1[c * 4];
        tb[(oh + c * 4 + 0) * 128 + p] = pack_bf2(a.x, b.x);
        tb[(oh + c * 4 + 1) * 128 + p] = pack_bf2(a.y, b.y);
        tb[(oh + c * 4 + 2) * 128 + p] = pack_bf2(a.z, b.z);
        tb[(oh + c * 4 + 3) * 128 + p] = pack_bf2(a.w, b.w);
    }
    __syncthreads();
    int w = t >> 6, l = t & 63;
    int lr = l >> 5;
    int ls = l & 31;
#pragma unroll
    for (int j = 0; j < 8; ++j) {
        int o = j * 8 + w * 2 + lr;
        uint4 v = *(const uint4*)&tb[o * 128 + ls * 4];
        *(uint4*)&W3t[(size_t)(o0 + o) * K + kc0 + ls * 8] = v;
    }
}

// ---- gather, full row in 128 KiB dynamic LDS: one block per row b, 1024 thr (16 waves) ----
__global__ __launch_bounds__(1024) void gather_full_k(const float* __restrict__ x,
                                                      const int* __restrict__ idx,
                                                      __hip_bfloat16* __restrict__ g) {
    extern __shared__ __hip_bfloat16 xr[];  // 131072 bytes
    int b = blockIdx.x;
    int t = threadIdx.x;
    const float4* xv = (const float4*)(x + (size_t)b * DD);
#pragma unroll
    for (int i = 0; i < 16; ++i) {
        float4 v = xv[t + 1024 * i];
        short4 p;
        p.x = (short)__bfloat16_as_ushort(__float2bfloat16(v.x));
        p.y = (short)__bfloat16_as_ushort(__float2bfloat16(v.y));
        p.z = (short)__bfloat16_as_ushort(__float2bfloat16(v.z));
        p.w = (short)__bfloat16_as_ushort(__float2bfloat16(v.w));
        *(short4*)&xr[(t + 1024 * i) * 4] = p;
    }
    __syncthreads();
    const int4* idx4 = (const int4*)idx;
    for (int u = t; u < NN * GG / 4; u += 1024) {
        int4 ii = idx4[u];
        int n = u >> 9;
        int k = (u & 511) * 4;
        ushort4 o;
        o.x = __bfloat16_as_ushort(xr[ii.x]);
        o.y = __bfloat16_as_ushort(xr[ii.y]);
        o.z = __bfloat16_as_ushort(xr[ii.z]);
        o.w = __bfloat16_as_ushort(xr[ii.w]);
        *(ushort4*)&g[((size_t)n * NB + b) * GG + k] = o;
    }
}

// ---- fallback gather (half row in 64 KiB static LDS) ----
__global__ __launch_bounds__(512) void gather_half_k(const float* __restrict__ x,
                                                     const int* __restrict__ idx,
                                                     __hip_bfloat16* __restrict__ g) {
    __shared__ __align__(16) __hip_bfloat16 xr[32768];
    int b = blockIdx.x >> 1;
    int h = blockIdx.x & 1;
    int t = threadIdx.x;
    const float4* xv = (const float4*)(x + (size_t)b * DD + h * 32768);
#pragma unroll
    for (int i = 0; i < 16; ++i) {
        float4 v = xv[t + 512 * i];
        short4 p;
        p.x = (short)__bfloat16_as_ushort(__float2bfloat16(v.x));
        p.y = (short)__bfloat16_as_ushort(__float2bfloat16(v.y));
        p.z = (short)__bfloat16_as_ushort(__float2bfloat16(v.z));
        p.w = (short)__bfloat16_as_ushort(__float2bfloat16(v.w));
        *(short4*)&xr[(t + 512 * i) * 4] = p;
    }
    __syncthreads();
    const int4* idx4 = (const int4*)idx;
    for (int u = t; u < NN * GG / 4; u += 512) {
        int4 ii = idx4[u];
        int n = u >> 9;
        int k = (u & 511) * 4;
        __hip_bfloat16* dst = &g[((size_t)n * NB + b) * GG + k];
        if ((ii.x >> 15) == h) dst[0] = xr[ii.x & 32767];
        if ((ii.y >> 15) == h) dst[1] = xr[ii.y & 32767];
        if ((ii.z >> 15) == h) dst[2] = xr[ii.z & 32767];
        if ((ii.w >> 15) == h) dst[3] = xr[ii.w & 32767];
    }
}

// ---- GEMM1 split-K=8 (probe: latency-bound vs fabric-BW-bound), fused W
// cast+transpose in B-staging. grid 1312 = 41n*2m*2o*8s; Kchunk 256, 8 iters.
// XCD-aware bijective swizzle: 1312 = 8*164.
__global__ __launch_bounds__(256) void gemm1_k(const __hip_bfloat16* __restrict__ g,
                                               const float* __restrict__ W,
                                               __hip_bfloat16* __restrict__ part1) {
    int bid0 = blockIdx.x;
    int bid = (bid0 & 7) * 164 + (bid0 >> 3);
    int s = bid & 7;
    int o0 = ((bid >> 3) & 1) * 128;
    int m0 = ((bid >> 4) & 1) * 128;
    int n = bid >> 5;
    const __hip_bfloat16* srcA = g + ((size_t)n * NB + m0) * GG + s * 256;
    const float* srcB = W + ((size_t)n * GG + s * 256) * OO + o0;  // [k][o0..o0+128)
    __shared__ __align__(16) __hip_bfloat16 lA[2][128 * 32];
    __shared__ __align__(16) __hip_bfloat16 lB[2][128 * 32];
    int t = threadIdx.x;
    int lane = t & 63, w = t >> 6;
    int mw = (w >> 1) * 64, ow = (w & 1) * 64;
    int lrow = lane & 15, quad = lane >> 4;
    int r0 = t >> 2, q0 = (t & 3) * 8;  // A staging
    // B staging: thread owns k-pair bp (rows 2bp,2bp+1), col octet boq
    int bp = t >> 4;            // 0..15
    int boq = t & 15;           // cols boq*8..boq*8+7
    int bswz = (boq & 3) << 2;  // XOR on kpair index, multiples of 4
    const float* wb0 = srcB + (size_t)(2 * bp) * OO + boq * 8;
    f32x4 acc[4][4] = {};

    // prologue: stage B tile 0 + A tile 0
    {
        float4 a0 = *(const float4*)&wb0[0];
        float4 a1 = *(const float4*)&wb0[4];
        float4 b0 = *(const float4*)&wb0[OO];
        float4 b1 = *(const float4*)&wb0[OO + 4];
        u32* d = (u32*)&lB[0][0];
        int ob = boq * 8;
        int pw = bp ^ bswz;
        d[(ob + 0) * 16 + pw] = pack_bf2(a0.x, b0.x);
        d[(ob + 1) * 16 + pw] = pack_bf2(a0.y, b0.y);
        d[(ob + 2) * 16 + pw] = pack_bf2(a0.z, b0.z);
        d[(ob + 3) * 16 + pw] = pack_bf2(a0.w, b0.w);
        d[(ob + 4) * 16 + pw] = pack_bf2(a1.x, b1.x);
        d[(ob + 5) * 16 + pw] = pack_bf2(a1.y, b1.y);
        d[(ob + 6) * 16 + pw] = pack_bf2(a1.z, b1.z);
        d[(ob + 7) * 16 + pw] = pack_bf2(a1.w, b1.w);
    }
    gl_lds16(srcA + (size_t)r0 * GG + q0, &lA[0][t * 8]);
    gl_lds16(srcA + (size_t)(r0 + 64) * GG + q0, &lA[0][(t + 256) * 8]);
    __syncthreads();
#pragma unroll 1
    for (int it = 0; it < 8; ++it) {
        int cur = it & 1;
        float4 a0, a1, b0, b1;
        bool pf = (it + 1 < 8);
        if (pf) {
            int k1 = (it + 1) * 32;
            const float* wn = wb0 + (size_t)k1 * OO;
            a0 = *(const float4*)&wn[0];        // issue early: consumed after MFMAs
            a1 = *(const float4*)&wn[4];
            b0 = *(const float4*)&wn[OO];
            b1 = *(const float4*)&wn[OO + 4];
            gl_lds16(srcA + (size_t)r0 * GG + k1 + q0, &lA[1 - cur][t * 8]);
            gl_lds16(srcA + (size_t)(r0 + 64) * GG + k1 + q0, &lA[1 - cur][(t + 256) * 8]);
        }
        bf16x8 af[4];
#pragma unroll
        for (int fm = 0; fm < 4; ++fm)
            af[fm] = *(const bf16x8*)&lA[cur][(mw + fm * 16 + lrow) * 32 + quad * 8];
        const u32* lbu = (const u32*)&lB[cur][0];
#pragma unroll
        for (int fn = 0; fn < 4; ++fn) {
            int orow = ow + fn * 16 + lrow;
            int fsw = ((orow >> 3) & 3) << 2;
            bf16x8 bfr = *(const bf16x8*)&lbu[orow * 16 + (quad * 4 ^ fsw)];
#pragma unroll
            for (int fm = 0; fm < 4; ++fm)
                acc[fm][fn] = __builtin_amdgcn_mfma_f32_16x16x32_bf16(af[fm], bfr, acc[fm][fn], 0, 0, 0);
        }
        if (pf) {
            u32* d = (u32*)&lB[1 - cur][0];
            int ob = boq * 8;
            int pw = bp ^ bswz;
            d[(ob + 0) * 16 + pw] = pack_bf2(a0.x, b0.x);
            d[(ob + 1) * 16 + pw] = pack_bf2(a0.y, b0.y);
            d[(ob + 2) * 16 + pw] = pack_bf2(a0.z, b0.z);
            d[(ob + 3) * 16 + pw] = pack_bf2(a0.w, b0.w);
            d[(ob + 4) * 16 + pw] = pack_bf2(a1.x, b1.x);
            d[(ob + 5) * 16 + pw] = pack_bf2(a1.y, b1.y);
            d[(ob + 6) * 16 + pw] = pack_bf2(a1.z, b1.z);
            d[(ob + 7) * 16 + pw] = pack_bf2(a1.w, b1.w);
        }
        __syncthreads();
    }
    // C/D layout: col=lane&15, row=quad*4+reg
#pragma unroll
    for (int fm = 0; fm < 4; ++fm) {
#pragma unroll
        for (int fn = 0; fn < 4; ++fn) {
            int col = o0 + ow + fn * 16 + lrow;
#pragma unroll
            for (int r = 0; r < 4; ++r) {
                int row = m0 + mw + fm * 16 + quad * 4 + r;
                part1[((size_t)s * NB + row) * NO + n * OO + col] = __float2bfloat16(acc[fm][fn][r]);
            }
        }
    }
}

// ---- combine 8 bf16 GEMM1 partials + bias -> h bf16 ----
__global__ __launch_bounds__(256) void combine1_k(const __hip_bfloat16* __restrict__ part1,
                                                  const float* __restrict__ bias,
                                                  __hip_bfloat16* __restrict__ h) {
    int j4 = blockIdx.x * 256 + threadIdx.x;  // 4-elem group over NB*NO/4
    int jj = j4 % (NO / 4);
    float4 a = ((const float4*)bias)[jj];
#pragma unroll
    for (int s = 0; s < 8; ++s) {
        ushort4 p = *(const ushort4*)&part1[(size_t)s * NB * NO + (size_t)j4 * 4];
        a.x += __bfloat162float(__ushort_as_bfloat16(p.x));
        a.y += __bfloat162float(__ushort_as_bfloat16(p.y));
        a.z += __bfloat162float(__ushort_as_bfloat16(p.z));
        a.w += __bfloat162float(__ushort_as_bfloat16(p.w));
    }
    ushort4 o;
    o.x = __bfloat16_as_ushort(__float2bfloat16(a.x));
    o.y = __bfloat16_as_ushort(__float2bfloat16(a.y));
    o.z = __bfloat16_as_ushort(__float2bfloat16(a.z));
    o.w = __bfloat16_as_ushort(__float2bfloat16(a.w));
    *(ushort4*)&h[(size_t)j4 * 4] = o;
}

// ---- GEMM2 split-K=41, double-buffered. grid 656 = 41s*2m*8e;
// 256 thr = 4 waves, wave tile 64x32; block 128x64, Kchunk 256, 8 iters.
// XCD-aware bijective swizzle: 656 = 8*82.
__global__ __launch_bounds__(256) void gemm2_k(const __hip_bfloat16* __restrict__ h,
                                               const __hip_bfloat16* __restrict__ W3t,
                                               float* __restrict__ part) {
    int bid0 = blockIdx.x;
    int bid = (bid0 & 7) * 82 + (bid0 >> 3);
    int e0 = (bid & 7) * 64;
    int m0 = ((bid >> 3) & 1) * 128;
    int s = bid >> 4;  // 0..40
    const __hip_bfloat16* srcA = h + (size_t)m0 * NO + s * 256;
    const __hip_bfloat16* srcB = W3t + (size_t)e0 * NO + s * 256;
    __shared__ __align__(16) __hip_bfloat16 lA[2][128 * 32];
    __shared__ __align__(16) __hip_bfloat16 lB[2][64 * 32];
    int t = threadIdx.x;
    int lane = t & 63, w = t >> 6;
    int mw = (w >> 1) * 64, ew = (w & 1) * 32;
    int lrow = lane & 15, quad = lane >> 4;
    int rA = t >> 2, qA = (t & 3) * 8;
    int rB = t >> 2, qB = (t & 3) * 8;
    f32x4 acc[4][2] = {};

    gl_lds16(srcA + (size_t)rA * NO + qA, &lA[0][t * 8]);
    gl_lds16(srcA + (size_t)(rA + 64) * NO + qA, &lA[0][(t + 256) * 8]);
    gl_lds16(srcB + (size_t)(rB & 63) * NO + qB, &lB[0][t * 8]);
    __syncthreads();
#pragma unroll 1
    for (int it = 0; it < 8; ++it) {
        int cur = it & 1;
        if (it + 1 < 8) {
            int k1 = (it + 1) * 32;
            gl_lds16(srcA + (size_t)rA * NO + k1 + qA, &lA[1 - cur][t * 8]);
            gl_lds16(srcA + (size_t)(rA + 64) * NO + k1 + qA, &lA[1 - cur][(t + 256) * 8]);
            gl_lds16(srcB + (size_t)(rB & 63) * NO + k1 + qB, &lB[1 - cur][t * 8]);
        }
        bf16x8 af[4];
#pragma unroll
        for (int fm = 0; fm < 4; ++fm)
            af[fm] = *(const bf16x8*)&lA[cur][(mw + fm * 16 + lrow) * 32 + quad * 8];
#pragma unroll
        for (int fn = 0; fn < 2; ++fn) {
            bf16x8 bfr = *(const bf16x8*)&lB[cur][(ew + fn * 16 + lrow) * 32 + quad * 8];
#pragma unroll
            for (int fm = 0; fm < 4; ++fm)
                acc[fm][fn] = __builtin_amdgcn_mfma_f32_16x16x32_bf16(af[fm], bfr, acc[fm][fn], 0, 0, 0);
        }
        __syncthreads();
    }
#pragma unroll
    for (int fm = 0; fm < 4; ++fm) {
#pragma unroll
        for (int fn = 0; fn < 2; ++fn) {
            int e = e0 + ew + fn * 16 + lrow;
#pragma unroll
            for (int r = 0; r < 4; ++r) {
                int row = m0 + mw + fm * 16 + quad * 4 + r;
                part[((size_t)s * NB + row) * EE + e] = acc[fm][fn][r];
            }
        }
    }
}

// ---- reduce partials + bias + leaky relu; 256 blocks x 128 thr ----
__global__ __launch_bounds__(128) void reduce_k(const float* __restrict__ part,
                                                const float* __restrict__ b3,
                                                float* __restrict__ out) {
    int j = blockIdx.x * 128 + threadIdx.x;
    float4 a = make_float4(0.f, 0.f, 0.f, 0.f);
    for (int s = 0; s < NN; ++s) {
        float4 v = ((const float4*)part)[(size_t)s * (NB * EE / 4) + j];
        a.x += v.x; a.y += v.y; a.z += v.z; a.w += v.w;
    }
    float4 bv = ((const float4*)b3)[j & 127];
    a.x += bv.x; a.y += bv.y; a.z += bv.z; a.w += bv.w;
    a.x = a.x >= 0.f ? a.x : NEG_SLOPE * a.x;
    a.y = a.y >= 0.f ? a.y : NEG_SLOPE * a.y;
    a.z = a.z >= 0.f ? a.z : NEG_SLOPE * a.z;
    a.w = a.w >= 0.f ? a.w : NEG_SLOPE * a.w;
    ((float4*)out)[j] = a;
}

extern "C" void kernel_launch(void* const* d_in, const int* in_sizes, int n_in,
                              void* d_out, int out_size, void* d_ws, size_t ws_size,
                              hipStream_t stream) {
    const float* x = (const float*)d_in[0];
    const int* idx = (const int*)d_in[1];
    const float* W = (const float*)d_in[2];
    const float* bias = (const float*)d_in[3];
    const float* W3 = (const float*)d_in[4];
    const float* b3 = (const float*)d_in[5];
    float* out = (float*)d_out;

    char* ws = (char*)d_ws;
    const size_t g_off = 0;
    const size_t g_sz = (size_t)NN * NB * GG * 2;
    const size_t wt_off = g_off + g_sz;           // now hosts part1: 8 planes bf16 NB*NO = 42,991,616 B (exact fit)
    const size_t wt_sz = (size_t)NN * GG * OO * 2;
    const size_t w3t_off = wt_off + wt_sz;
    const size_t w3t_sz = (size_t)NO * EE * 2;
    const size_t h_off = w3t_off + w3t_sz;
    const size_t h_sz = (size_t)NB * NO * 2;
    const size_t p_off = h_off + h_sz;            // gemm2 fp32 partials (21.5 MB)

    __hip_bfloat16* g = (__hip_bfloat16*)(ws + g_off);
    __hip_bfloat16* W3t = (__hip_bfloat16*)(ws + w3t_off);
    __hip_bfloat16* h = (__hip_bfloat16*)(ws + h_off);
    __hip_bfloat16* part1 = (__hip_bfloat16*)(ws + wt_off);
    float* part = (float*)(ws + p_off);

    // W3 (10496,512) -> W3t (512,10496) bf16
    transpose_w3_k<<<dim3(NN * 8), 256, 0, stream>>>(W3, W3t);
    // gather: full 128 KiB row in dynamic LDS if allowed (1024 thr), else fallback
    hipError_t aerr = hipFuncSetAttribute(reinterpret_cast<const void*>(gather_full_k),
                                          hipFuncAttributeMaxDynamicSharedMemorySize, 131072);
    if (aerr == hipSuccess) {
        gather_full_k<<<dim3(NB), 1024, 131072, stream>>>(x, idx, g);
    } else {
        gather_half_k<<<dim3(512), 512, 0, stream>>>(x, idx, g);
    }
    // GEMM1 split-K=8, B staged directly from W fp32 (fused cast+transpose)
    gemm1_k<<<dim3(1312), 256, 0, stream>>>(g, W, part1);
    // combine 8 partials + bias -> h bf16
    combine1_k<<<dim3(NB * NO / 4 / 256), 256, 0, stream>>>(part1, bias, h);
    // GEMM2 split-K, double-buffered
    gemm2_k<<<dim3(656), 256, 0, stream>>>(h, W3t, part);
    // reduce + bias + leaky relu
    reduce_k<<<dim3(256), 128, 0, stream>>>(part, b3, out);
}

// Round 7
// 261.168 us; speedup vs baseline: 1.0589x; 1.0157x over previous
//
#include <hip/hip_runtime.h>
#include <hip/hip_bf16.h>

#define NB 256
#define DD 65536
#define NN 41
#define GG 2048
#define OO 256
#define NO 10496
#define EE 512
#define NEG_SLOPE 0.2f

typedef __attribute__((ext_vector_type(8))) short bf16x8;
typedef __attribute__((ext_vector_type(4))) float f32x4;
typedef unsigned int u32;

// async global->LDS, 16B per lane. LDS dest must be wave-uniform base + lane*16.
__device__ __forceinline__ void gl_lds16(const __hip_bfloat16* gsrc, __hip_bfloat16* lds) {
    __builtin_amdgcn_global_load_lds((const __attribute__((address_space(1))) u32*)gsrc,
                                     (__attribute__((address_space(3))) u32*)lds, 16, 0, 0);
}

__device__ __forceinline__ u32 pack_bf2(float lo, float hi) {
    u32 a = (u32)__bfloat16_as_ushort(__float2bfloat16(lo));
    u32 b = (u32)__bfloat16_as_ushort(__float2bfloat16(hi));
    return a | (b << 16);
}

// ---- transpose + cast for W3 ONLY (W-transpose is fused into gemm1) ----
// W3 (10496,512) -> W3t (512,10496): 41 kc * 8 o = 328 blocks of [256 k][64 o].
__global__ __launch_bounds__(256) void transpose_w3_k(const float* __restrict__ W3,
                                                      __hip_bfloat16* __restrict__ W3t) {
    __shared__ u32 tb[64 * 128];  // [64 o][128 k-pair u32] = 32 KiB
    int rem = blockIdx.x;
    int kc0 = (rem >> 3) * 256;
    int o0 = (rem & 7) * 64;
    const int K = NO, Oc = EE;
    int t = threadIdx.x;
    int p = t & 127;            // k-pair index (input rows 2p, 2p+1)
    int oh = (t >> 7) * 32;     // o-half base
    const float* r0 = W3 + (size_t)(kc0 + 2 * p) * Oc + o0 + oh;
    const float* r1 = r0 + Oc;
#pragma unroll
    for (int c = 0; c < 8; ++c) {
        float4 a = *(const float4*)&r0[c * 4];
        float4 b = *(const float4*)&r1[c * 4];
        tb[(oh + c * 4 + 0) * 128 + p] = pack_bf2(a.x, b.x);
        tb[(oh + c * 4 + 1) * 128 + p] = pack_bf2(a.y, b.y);
        tb[(oh + c * 4 + 2) * 128 + p] = pack_bf2(a.z, b.z);
        tb[(oh + c * 4 + 3) * 128 + p] = pack_bf2(a.w, b.w);
    }
    __syncthreads();
    int w = t >> 6, l = t & 63;
    int lr = l >> 5;
    int ls = l & 31;
#pragma unroll
    for (int j = 0; j < 8; ++j) {
        int o = j * 8 + w * 2 + lr;
        uint4 v = *(const uint4*)&tb[o * 128 + ls * 4];
        *(uint4*)&W3t[(size_t)(o0 + o) * K + kc0 + ls * 8] = v;
    }
}

// ---- gather, full row in 128 KiB dynamic LDS: one block per row b, 1024 thr (16 waves) ----
__global__ __launch_bounds__(1024) void gather_full_k(const float* __restrict__ x,
                                                      const int* __restrict__ idx,
                                                      __hip_bfloat16* __restrict__ g) {
    extern __shared__ __hip_bfloat16 xr[];  // 131072 bytes
    int b = blockIdx.x;
    int t = threadIdx.x;
    const float4* xv = (const float4*)(x + (size_t)b * DD);
#pragma unroll
    for (int i = 0; i < 16; ++i) {
        float4 v = xv[t + 1024 * i];
        short4 p;
        p.x = (short)__bfloat16_as_ushort(__float2bfloat16(v.x));
        p.y = (short)__bfloat16_as_ushort(__float2bfloat16(v.y));
        p.z = (short)__bfloat16_as_ushort(__float2bfloat16(v.z));
        p.w = (short)__bfloat16_as_ushort(__float2bfloat16(v.w));
        *(short4*)&xr[(t + 1024 * i) * 4] = p;
    }
    __syncthreads();
    const int4* idx4 = (const int4*)idx;
    for (int u = t; u < NN * GG / 4; u += 1024) {
        int4 ii = idx4[u];
        int n = u >> 9;
        int k = (u & 511) * 4;
        ushort4 o;
        o.x = __bfloat16_as_ushort(xr[ii.x]);
        o.y = __bfloat16_as_ushort(xr[ii.y]);
        o.z = __bfloat16_as_ushort(xr[ii.z]);
        o.w = __bfloat16_as_ushort(xr[ii.w]);
        *(ushort4*)&g[((size_t)n * NB + b) * GG + k] = o;
    }
}

// ---- fallback gather (half row in 64 KiB static LDS) ----
__global__ __launch_bounds__(512) void gather_half_k(const float* __restrict__ x,
                                                     const int* __restrict__ idx,
                                                     __hip_bfloat16* __restrict__ g) {
    __shared__ __align__(16) __hip_bfloat16 xr[32768];
    int b = blockIdx.x >> 1;
    int h = blockIdx.x & 1;
    int t = threadIdx.x;
    const float4* xv = (const float4*)(x + (size_t)b * DD + h * 32768);
#pragma unroll
    for (int i = 0; i < 16; ++i) {
        float4 v = xv[t + 512 * i];
        short4 p;
        p.x = (short)__bfloat16_as_ushort(__float2bfloat16(v.x));
        p.y = (short)__bfloat16_as_ushort(__float2bfloat16(v.y));
        p.z = (short)__bfloat16_as_ushort(__float2bfloat16(v.z));
        p.w = (short)__bfloat16_as_ushort(__float2bfloat16(v.w));
        *(short4*)&xr[(t + 512 * i) * 4] = p;
    }
    __syncthreads();
    const int4* idx4 = (const int4*)idx;
    for (int u = t; u < NN * GG / 4; u += 512) {
        int4 ii = idx4[u];
        int n = u >> 9;
        int k = (u & 511) * 4;
        __hip_bfloat16* dst = &g[((size_t)n * NB + b) * GG + k];
        if ((ii.x >> 15) == h) dst[0] = xr[ii.x & 32767];
        if ((ii.y >> 15) == h) dst[1] = xr[ii.y & 32767];
        if ((ii.z >> 15) == h) dst[2] = xr[ii.z & 32767];
        if ((ii.w >> 15) == h) dst[3] = xr[ii.w & 32767];
    }
}

// ---- GEMM1: block tile 256m x 128o (full M per block -> W read exactly once),
// split-K=4, 512 thr = 8 waves of 64x64, fused W fp32 cast+transpose B-staging.
// grid 328 = 41n * 2o * 4s; Kchunk 512, BK=32, 16 iters. XCD swizzle 328 = 8*41.
__global__ __launch_bounds__(512) void gemm1_k(const __hip_bfloat16* __restrict__ g,
                                               const float* __restrict__ W,
                                               __hip_bfloat16* __restrict__ part1) {
    int bid0 = blockIdx.x;
    int bid = (bid0 & 7) * 41 + (bid0 >> 3);
    int s = bid & 3;
    int o0 = ((bid >> 2) & 1) * 128;
    int n = bid >> 3;
    const __hip_bfloat16* srcA = g + (size_t)n * NB * GG + s * 512;
    const float* srcB = W + ((size_t)n * GG + s * 512) * OO + o0;  // [k][o0..o0+128)
    __shared__ __align__(16) __hip_bfloat16 lA[2][256 * 32];  // 32 KiB
    __shared__ __align__(16) u32 lB[2][128 * 16];             // 16 KiB, [o][kpair] swizzled
    int t = threadIdx.x;
    int lane = t & 63, w = t >> 6;
    int mw = (w >> 1) * 64, ow = (w & 1) * 64;
    int lrow = lane & 15, quad = lane >> 4;
    int r0 = t >> 2, q0 = (t & 3) * 8;  // A staging: rows r0, r0+128
    // B staging: thread owns k-pair bp (rows 2bp,2bp+1), 4 cols at cb
    int bp = (t >> 4) & 15;
    int boq8 = t & 15;
    int hi = w >> 2;                 // wave-uniform col-half select
    int cb = boq8 * 8 + hi * 4;      // col base, 4 cols
    int pw = bp ^ ((boq8 & 3) << 2); // swizzled kpair slot (matches frag-read XOR)
    const float* wb0 = srcB + (size_t)(2 * bp) * OO + cb;
    f32x4 acc[4][4] = {};

    // prologue: stage B tile 0 + A tile 0
    {
        float4 a0 = *(const float4*)&wb0[0];
        float4 b0 = *(const float4*)&wb0[OO];
        u32* d = &lB[0][0];
        d[(cb + 0) * 16 + pw] = pack_bf2(a0.x, b0.x);
        d[(cb + 1) * 16 + pw] = pack_bf2(a0.y, b0.y);
        d[(cb + 2) * 16 + pw] = pack_bf2(a0.z, b0.z);
        d[(cb + 3) * 16 + pw] = pack_bf2(a0.w, b0.w);
    }
    gl_lds16(srcA + (size_t)r0 * GG + q0, &lA[0][t * 8]);
    gl_lds16(srcA + (size_t)(r0 + 128) * GG + q0, &lA[0][(t + 512) * 8]);
    __syncthreads();
#pragma unroll 1
    for (int it = 0; it < 16; ++it) {
        int cur = it & 1;
        float4 a0, b0;
        bool pf = (it + 1 < 16);
        if (pf) {
            int k1 = (it + 1) * 32;
            const float* wn = wb0 + (size_t)k1 * OO;
            a0 = *(const float4*)&wn[0];   // issue early: consumed after MFMAs
            b0 = *(const float4*)&wn[OO];
            gl_lds16(srcA + (size_t)r0 * GG + k1 + q0, &lA[1 - cur][t * 8]);
            gl_lds16(srcA + (size_t)(r0 + 128) * GG + k1 + q0, &lA[1 - cur][(t + 512) * 8]);
        }
        bf16x8 af[4];
#pragma unroll
        for (int fm = 0; fm < 4; ++fm)
            af[fm] = *(const bf16x8*)&lA[cur][(mw + fm * 16 + lrow) * 32 + quad * 8];
        const u32* lbu = &lB[cur][0];
#pragma unroll
        for (int fn = 0; fn < 4; ++fn) {
            int orow = ow + fn * 16 + lrow;
            int fsw = ((orow >> 3) & 3) << 2;
            bf16x8 bfr = *(const bf16x8*)&lbu[orow * 16 + (quad * 4 ^ fsw)];
#pragma unroll
            for (int fm = 0; fm < 4; ++fm)
                acc[fm][fn] = __builtin_amdgcn_mfma_f32_16x16x32_bf16(af[fm], bfr, acc[fm][fn], 0, 0, 0);
        }
        if (pf) {
            u32* d = &lB[1 - cur][0];
            d[(cb + 0) * 16 + pw] = pack_bf2(a0.x, b0.x);
            d[(cb + 1) * 16 + pw] = pack_bf2(a0.y, b0.y);
            d[(cb + 2) * 16 + pw] = pack_bf2(a0.z, b0.z);
            d[(cb + 3) * 16 + pw] = pack_bf2(a0.w, b0.w);
        }
        __syncthreads();
    }
    // C/D layout: col=lane&15, row=quad*4+reg
#pragma unroll
    for (int fm = 0; fm < 4; ++fm) {
#pragma unroll
        for (int fn = 0; fn < 4; ++fn) {
            int col = o0 + ow + fn * 16 + lrow;
#pragma unroll
            for (int r = 0; r < 4; ++r) {
                int row = mw + fm * 16 + quad * 4 + r;
                part1[((size_t)s * NB + row) * NO + n * OO + col] = __float2bfloat16(acc[fm][fn][r]);
            }
        }
    }
}

// ---- combine 4 bf16 GEMM1 partials + bias -> h bf16 ----
__global__ __launch_bounds__(256) void combine1_k(const __hip_bfloat16* __restrict__ part1,
                                                  const float* __restrict__ bias,
                                                  __hip_bfloat16* __restrict__ h) {
    int j4 = blockIdx.x * 256 + threadIdx.x;  // 4-elem group over NB*NO/4
    int jj = j4 % (NO / 4);
    float4 a = ((const float4*)bias)[jj];
#pragma unroll
    for (int s = 0; s < 4; ++s) {
        ushort4 p = *(const ushort4*)&part1[(size_t)s * NB * NO + (size_t)j4 * 4];
        a.x += __bfloat162float(__ushort_as_bfloat16(p.x));
        a.y += __bfloat162float(__ushort_as_bfloat16(p.y));
        a.z += __bfloat162float(__ushort_as_bfloat16(p.z));
        a.w += __bfloat162float(__ushort_as_bfloat16(p.w));
    }
    ushort4 o;
    o.x = __bfloat16_as_ushort(__float2bfloat16(a.x));
    o.y = __bfloat16_as_ushort(__float2bfloat16(a.y));
    o.z = __bfloat16_as_ushort(__float2bfloat16(a.z));
    o.w = __bfloat16_as_ushort(__float2bfloat16(a.w));
    *(ushort4*)&h[(size_t)j4 * 4] = o;
}

// ---- GEMM2 split-K=41, double-buffered. grid 656 = 41s*2m*8e;
// 256 thr = 4 waves, wave tile 64x32; block 128x64, Kchunk 256, 8 iters.
// XCD-aware bijective swizzle: 656 = 8*82.
__global__ __launch_bounds__(256) void gemm2_k(const __hip_bfloat16* __restrict__ h,
                                               const __hip_bfloat16* __restrict__ W3t,
                                               float* __restrict__ part) {
    int bid0 = blockIdx.x;
    int bid = (bid0 & 7) * 82 + (bid0 >> 3);
    int e0 = (bid & 7) * 64;
    int m0 = ((bid >> 3) & 1) * 128;
    int s = bid >> 4;  // 0..40
    const __hip_bfloat16* srcA = h + (size_t)m0 * NO + s * 256;
    const __hip_bfloat16* srcB = W3t + (size_t)e0 * NO + s * 256;
    __shared__ __align__(16) __hip_bfloat16 lA[2][128 * 32];
    __shared__ __align__(16) __hip_bfloat16 lB[2][64 * 32];
    int t = threadIdx.x;
    int lane = t & 63, w = t >> 6;
    int mw = (w >> 1) * 64, ew = (w & 1) * 32;
    int lrow = lane & 15, quad = lane >> 4;
    int rA = t >> 2, qA = (t & 3) * 8;
    int rB = t >> 2, qB = (t & 3) * 8;
    f32x4 acc[4][2] = {};

    gl_lds16(srcA + (size_t)rA * NO + qA, &lA[0][t * 8]);
    gl_lds16(srcA + (size_t)(rA + 64) * NO + qA, &lA[0][(t + 256) * 8]);
    gl_lds16(srcB + (size_t)(rB & 63) * NO + qB, &lB[0][t * 8]);
    __syncthreads();
#pragma unroll 1
    for (int it = 0; it < 8; ++it) {
        int cur = it & 1;
        if (it + 1 < 8) {
            int k1 = (it + 1) * 32;
            gl_lds16(srcA + (size_t)rA * NO + k1 + qA, &lA[1 - cur][t * 8]);
            gl_lds16(srcA + (size_t)(rA + 64) * NO + k1 + qA, &lA[1 - cur][(t + 256) * 8]);
            gl_lds16(srcB + (size_t)(rB & 63) * NO + k1 + qB, &lB[1 - cur][t * 8]);
        }
        bf16x8 af[4];
#pragma unroll
        for (int fm = 0; fm < 4; ++fm)
            af[fm] = *(const bf16x8*)&lA[cur][(mw + fm * 16 + lrow) * 32 + quad * 8];
#pragma unroll
        for (int fn = 0; fn < 2; ++fn) {
            bf16x8 bfr = *(const bf16x8*)&lB[cur][(ew + fn * 16 + lrow) * 32 + quad * 8];
#pragma unroll
            for (int fm = 0; fm < 4; ++fm)
                acc[fm][fn] = __builtin_amdgcn_mfma_f32_16x16x32_bf16(af[fm], bfr, acc[fm][fn], 0, 0, 0);
        }
        __syncthreads();
    }
#pragma unroll
    for (int fm = 0; fm < 4; ++fm) {
#pragma unroll
        for (int fn = 0; fn < 2; ++fn) {
            int e = e0 + ew + fn * 16 + lrow;
#pragma unroll
            for (int r = 0; r < 4; ++r) {
                int row = m0 + mw + fm * 16 + quad * 4 + r;
                part[((size_t)s * NB + row) * EE + e] = acc[fm][fn][r];
            }
        }
    }
}

// ---- reduce partials + bias + leaky relu; 256 blocks x 128 thr ----
__global__ __launch_bounds__(128) void reduce_k(const float* __restrict__ part,
                                                const float* __restrict__ b3,
                                                float* __restrict__ out) {
    int j = blockIdx.x * 128 + threadIdx.x;
    float4 a = make_float4(0.f, 0.f, 0.f, 0.f);
    for (int s = 0; s < NN; ++s) {
        float4 v = ((const float4*)part)[(size_t)s * (NB * EE / 4) + j];
        a.x += v.x; a.y += v.y; a.z += v.z; a.w += v.w;
    }
    float4 bv = ((const float4*)b3)[j & 127];
    a.x += bv.x; a.y += bv.y; a.z += bv.z; a.w += bv.w;
    a.x = a.x >= 0.f ? a.x : NEG_SLOPE * a.x;
    a.y = a.y >= 0.f ? a.y : NEG_SLOPE * a.y;
    a.z = a.z >= 0.f ? a.z : NEG_SLOPE * a.z;
    a.w = a.w >= 0.f ? a.w : NEG_SLOPE * a.w;
    ((float4*)out)[j] = a;
}

extern "C" void kernel_launch(void* const* d_in, const int* in_sizes, int n_in,
                              void* d_out, int out_size, void* d_ws, size_t ws_size,
                              hipStream_t stream) {
    const float* x = (const float*)d_in[0];
    const int* idx = (const int*)d_in[1];
    const float* W = (const float*)d_in[2];
    const float* bias = (const float*)d_in[3];
    const float* W3 = (const float*)d_in[4];
    const float* b3 = (const float*)d_in[5];
    float* out = (float*)d_out;

    char* ws = (char*)d_ws;
    const size_t g_off = 0;
    const size_t g_sz = (size_t)NN * NB * GG * 2;
    const size_t wt_off = g_off + g_sz;           // hosts part1: 4 planes bf16 NB*NO = 21.5 MB
    const size_t wt_sz = (size_t)NN * GG * OO * 2;
    const size_t w3t_off = wt_off + wt_sz;
    const size_t w3t_sz = (size_t)NO * EE * 2;
    const size_t h_off = w3t_off + w3t_sz;
    const size_t h_sz = (size_t)NB * NO * 2;
    const size_t p_off = h_off + h_sz;            // gemm2 fp32 partials (21.5 MB)

    __hip_bfloat16* g = (__hip_bfloat16*)(ws + g_off);
    __hip_bfloat16* W3t = (__hip_bfloat16*)(ws + w3t_off);
    __hip_bfloat16* h = (__hip_bfloat16*)(ws + h_off);
    __hip_bfloat16* part1 = (__hip_bfloat16*)(ws + wt_off);
    float* part = (float*)(ws + p_off);

    // W3 (10496,512) -> W3t (512,10496) bf16
    transpose_w3_k<<<dim3(NN * 8), 256, 0, stream>>>(W3, W3t);
    // gather: full 128 KiB row in dynamic LDS if allowed (1024 thr), else fallback
    hipError_t aerr = hipFuncSetAttribute(reinterpret_cast<const void*>(gather_full_k),
                                          hipFuncAttributeMaxDynamicSharedMemorySize, 131072);
    if (aerr == hipSuccess) {
        gather_full_k<<<dim3(NB), 1024, 131072, stream>>>(x, idx, g);
    } else {
        gather_half_k<<<dim3(512), 512, 0, stream>>>(x, idx, g);
    }
    // GEMM1: full-M 256x128 tile, split-K=4, B staged directly from W fp32
    gemm1_k<<<dim3(328), 512, 0, stream>>>(g, W, part1);
    // combine 4 partials + bias -> h bf16
    combine1_k<<<dim3(NB * NO / 4 / 256), 256, 0, stream>>>(part1, bias, h);
    // GEMM2 split-K, double-buffered
    gemm2_k<<<dim3(656), 256, 0, stream>>>(h, W3t, part);
    // reduce + bias + leaky relu
    reduce_k<<<dim3(256), 128, 0, stream>>>(part, b3, out);
}